// Round 4
// baseline (725.151 us; speedup 1.0000x reference)
//
#include <hip/hip_runtime.h>
#include <hip/hip_bf16.h>
#include <cstdint>
#include <cstddef>

#define M_ 4096
#define K_ 7168
#define N_ 18432
#define NT 56     // K-tiles of BK=128
#define ITERS 28  // 2 K-tiles per iteration

typedef __attribute__((ext_vector_type(4))) int i32x4;

#define AS1 __attribute__((address_space(1)))
#define AS3 __attribute__((address_space(3)))

__device__ __forceinline__ void gld_lds16(void* lds, const void* g) {
  __builtin_amdgcn_global_load_lds((const AS1 void*)g, (AS3 void*)lds, 16, 0, 0);
}

// ---------------- prepass 1: per-row dynamic quantization of x ----------------
__global__ __launch_bounds__(256) void quant_x_kernel(const float* __restrict__ x,
                                                      signed char* __restrict__ xq,
                                                      float* __restrict__ sx) {
  const int m = blockIdx.x;
  const float4* row4 = (const float4*)(x + (size_t)m * K_);
  float mx = 0.f;
  for (int i = threadIdx.x; i < K_ / 4; i += 256) {
    float4 v = row4[i];
    mx = fmaxf(mx, fmaxf(fmaxf(fabsf(v.x), fabsf(v.y)), fmaxf(fabsf(v.z), fabsf(v.w))));
  }
#pragma unroll
  for (int d = 1; d < 64; d <<= 1) mx = fmaxf(mx, __shfl_xor(mx, d));
  __shared__ float wred[4];
  if ((threadIdx.x & 63) == 0) wred[threadIdx.x >> 6] = mx;
  __syncthreads();
  mx = fmaxf(fmaxf(wred[0], wred[1]), fmaxf(wred[2], wred[3]));
  const float inv = mx > 0.f ? 127.f / mx : 0.f;
  if (threadIdx.x == 0) sx[m] = mx / 127.f;
  char4* q4 = (char4*)(xq + (size_t)m * K_);
  for (int i = threadIdx.x; i < K_ / 4; i += 256) {
    float4 v = row4[i];
    char4 c;
    c.x = (signed char)__float2int_rn(v.x * inv);
    c.y = (signed char)__float2int_rn(v.y * inv);
    c.z = (signed char)__float2int_rn(v.z * inv);
    c.w = (signed char)__float2int_rn(v.w * inv);
    q4[i] = c;
  }
}

// ---- prepass 2: W int32 [K,N] -> Wt int8 [N,K] (convert + transpose) ----
__global__ __launch_bounds__(256) void transpose_w_kernel(const int* __restrict__ W,
                                                          signed char* __restrict__ Wt) {
  __shared__ __align__(16) signed char t[64][80];
  const int k0 = blockIdx.x * 64;
  const int n0 = blockIdx.y * 64;
  const int r = threadIdx.x >> 4;
  const int c4 = (threadIdx.x & 15) * 4;
#pragma unroll
  for (int rr = 0; rr < 4; ++rr) {
    const int row = rr * 16 + r;
    int4 v = *(const int4*)(W + (size_t)(k0 + row) * N_ + n0 + c4);
    t[c4 + 0][row] = (signed char)v.x;
    t[c4 + 1][row] = (signed char)v.y;
    t[c4 + 2][row] = (signed char)v.z;
    t[c4 + 3][row] = (signed char)v.w;
  }
  __syncthreads();
  const int nr = threadIdx.x >> 2;
  const int cb = (threadIdx.x & 3) * 16;
  int4 o = *(const int4*)&t[nr][cb];
  *(int4*)(Wt + (size_t)(n0 + nr) * K_ + k0 + cb) = o;
}

// ============ main GEMM: 256x256 tile, BK=128, 8-wave, 8-phase counted-vmcnt ============
// + register-double-banked ds_read prefetch: phase p issues phase p+1's fragment reads
//   before its MFMA cluster, so LDS reads drain during the MFMA cluster.
// LDS: A [0,65536), B [65536,131072); addr = base + buf*32768 + ks*16384 + row*64 + slot*16
// T2 swizzle: physslot = slot ^ ((row>>1)&3), applied on gld source (inverse) + ds_read.
__global__ __launch_bounds__(512, 2) void gemm_i8_kernel(const signed char* __restrict__ Aq,
                                                         const signed char* __restrict__ Bt,
                                                         const float* __restrict__ sx,
                                                         const float* __restrict__ scale,
                                                         float* __restrict__ C) {
  __shared__ __align__(16) signed char lds[131072];

  // n-major XCD mapping: each XCD owns 9 n-columns; Wt panel (1.8MB) stays L2-resident.
  const int bid = blockIdx.x;
  const int xcd = bid & 7;
  const int j = bid >> 3;                  // 0..143
  const int m0 = (j & 15) * 256;           // 16 m-blocks
  const int n0 = (xcd * 9 + (j >> 4)) * 256;  // 72 n-blocks

  const int tid = threadIdx.x;
  const int w = tid >> 6;      // wave 0..7
  const int lane = tid & 63;
  const int wr = w >> 2;       // 0..1 (M)
  const int wc = w & 3;        // 0..3 (N)

  const int fr = lane & 15;
  const int q = lane >> 4;
  const int sl = ((q ^ ((fr >> 1) & 3)) << 4);

  // staging per-lane (inverse-swizzled global source, linear LDS dest)
  const int ls16 = (((lane & 3) ^ ((lane >> 3) & 3)) << 4);
  const int pr0 = w * 16 + (lane >> 2);
  const unsigned offA0 = (unsigned)(m0 + pr0) * K_ + ls16;
  const unsigned offA1 = (unsigned)(m0 + 128 + pr0) * K_ + ls16;
  const unsigned offB0 = (unsigned)(n0 + pr0) * K_ + ls16;
  const unsigned offB1 = (unsigned)(n0 + 128 + pr0) * K_ + ls16;

#define STAGE_A(T, KS) do {                                                        \
    const int tc_ = (T) < NT ? (T) : NT - 1;                                       \
    signed char* d_ = lds + (((T) & 1) * 32768 + (KS) * 16384 + w * 1024);         \
    gld_lds16(d_, Aq + (size_t)offA0 + tc_ * 128 + (KS) * 64);                     \
    gld_lds16(d_ + 8192, Aq + (size_t)offA1 + tc_ * 128 + (KS) * 64);              \
  } while (0)
#define STAGE_B(T, KS) do {                                                        \
    const int tc_ = (T) < NT ? (T) : NT - 1;                                       \
    signed char* d_ = lds + (65536 + ((T) & 1) * 32768 + (KS) * 16384 + w * 1024); \
    gld_lds16(d_, Bt + (size_t)offB0 + tc_ * 128 + (KS) * 64);                     \
    gld_lds16(d_ + 8192, Bt + (size_t)offB1 + tc_ * 128 + (KS) * 64);              \
  } while (0)
#define LDA_TO(DST, BUF, KS, MH) do {                                              \
    const signed char* ab = lds + ((BUF) * 32768 + (KS) * 16384);                  \
    _Pragma("unroll") for (int i_ = 0; i_ < 4; ++i_)                               \
      DST[i_] = *(const i32x4*)(ab + (wr * 128 + ((MH) * 4 + i_) * 16 + fr) * 64 + sl); \
  } while (0)
#define LDB_TO(DST, BUF, KS) do {                                                  \
    const signed char* bb = lds + (65536 + (BUF) * 32768 + (KS) * 16384);          \
    _Pragma("unroll") for (int n_ = 0; n_ < 4; ++n_)                               \
      DST[n_] = *(const i32x4*)(bb + (wc * 64 + n_ * 16 + fr) * 64 + sl);          \
  } while (0)
#define MFMA16(MH, AQ, BQ) do {                                                    \
    __builtin_amdgcn_s_setprio(1);                                                 \
    _Pragma("unroll") for (int i_ = 0; i_ < 4; ++i_)                               \
    _Pragma("unroll") for (int n_ = 0; n_ < 4; ++n_)                               \
      acc[(MH) * 4 + i_][n_] = __builtin_amdgcn_mfma_i32_16x16x64_i8(              \
          AQ[i_], BQ[n_], acc[(MH) * 4 + i_][n_], 0, 0, 0);                        \
    __builtin_amdgcn_s_setprio(0);                                                 \
  } while (0)
#define FENCE asm volatile("" ::: "memory")
#define BAR do { FENCE; __builtin_amdgcn_s_barrier(); FENCE; } while (0)
#define VM6 do { asm volatile("s_waitcnt vmcnt(6)" ::: "memory"); \
                 __builtin_amdgcn_sched_barrier(0); } while (0)
#define SB __builtin_amdgcn_sched_barrier(0)

  i32x4 acc[8][4] = {};
  i32x4 aq0[4], aq1[4], bq0[4], bq1[4];

  // Prologue: tile0 {B0,A0,B1,A1}, tile1 {B0,A0,B1}; drain tile0 (leave 3 half-tiles in flight)
  STAGE_B(0, 0); STAGE_A(0, 0); STAGE_B(0, 1); STAGE_A(0, 1);
  STAGE_B(1, 0); STAGE_A(1, 0); STAGE_B(1, 1);
  VM6;
  BAR;
  LDB_TO(bq0, 0, 0); LDA_TO(aq0, 0, 0, 0);  // prefetch ph1 fragments
  SB;

  for (int it = 0; it < ITERS; ++it) {
    const int u = 2 * it;  // tile u -> buf0, tile u+1 -> buf1
    // ph1: MFMA(ks0,m0-3) | prefetch ph2 | stage (u+1):A1
    STAGE_A(u + 1, 1);
    BAR;
    LDA_TO(aq1, 0, 0, 1);
    SB;
    MFMA16(0, aq0, bq0);
    BAR;
    // ph2: MFMA(ks0,m4-7) | prefetch ph3 | stage (u+2):B0
    STAGE_B(u + 2, 0);
    BAR;
    LDB_TO(bq1, 0, 1); LDA_TO(aq0, 0, 1, 0);
    SB;
    MFMA16(1, aq1, bq0);
    BAR;
    // ph3: MFMA(ks1,m0-3) | prefetch ph4 | stage (u+2):A0
    STAGE_A(u + 2, 0);
    BAR;
    LDA_TO(aq1, 0, 1, 1);
    SB;
    MFMA16(0, aq0, bq1);
    BAR;
    // ph4: MFMA(ks1,m4-7) | VM6 drains tile u+1 | prefetch ph5 (buf1) | stage (u+2):B1
    STAGE_B(u + 2, 1);
    BAR;
    VM6;   // FIFO: leaves (u+2):{B0,A0,B1} in flight; tile u+1 fully in LDS
    LDB_TO(bq0, 1, 0); LDA_TO(aq0, 1, 0, 0);
    SB;
    MFMA16(1, aq1, bq1);
    BAR;
    // ph5: MFMA(ks0,m0-3) | prefetch ph6 | stage (u+2):A1
    STAGE_A(u + 2, 1);
    BAR;
    LDA_TO(aq1, 1, 0, 1);
    SB;
    MFMA16(0, aq0, bq0);
    BAR;
    // ph6: MFMA(ks0,m4-7) | prefetch ph7 | stage (u+3):B0
    STAGE_B(u + 3, 0);
    BAR;
    LDB_TO(bq1, 1, 1); LDA_TO(aq0, 1, 1, 0);
    SB;
    MFMA16(1, aq1, bq0);
    BAR;
    // ph7: MFMA(ks1,m0-3) | prefetch ph8 | stage (u+3):A0
    STAGE_A(u + 3, 0);
    BAR;
    LDA_TO(aq1, 1, 1, 1);
    SB;
    MFMA16(0, aq0, bq1);
    BAR;
    // ph8: MFMA(ks1,m4-7) | VM6 drains tile u+2 | prefetch next ph1 (buf0) | stage (u+3):B1
    STAGE_B(u + 3, 1);
    BAR;
    VM6;   // leaves (u+3):{B0,A0,B1}; tile u+2 fully in LDS
    LDB_TO(bq0, 0, 0); LDA_TO(aq0, 0, 0, 0);
    SB;
    MFMA16(1, aq1, bq1);
    BAR;
  }

  // epilogue: y = i32acc * sx[m] * scale[n]; C/D: col=lane&15, row=(lane>>4)*4+reg
  const int mb = m0 + wr * 128;
  const int nb = n0 + wc * 64;
  const int col = lane & 15;
  const int rq = (lane >> 4) * 4;
  float scl[4];
#pragma unroll
  for (int n = 0; n < 4; ++n) scl[n] = scale[nb + n * 16 + col];
#pragma unroll
  for (int m = 0; m < 8; ++m) {
#pragma unroll
    for (int r = 0; r < 4; ++r) {
      const int row = mb + m * 16 + rq + r;
      const float s = sx[row];
      float* out = C + (size_t)row * N_ + nb + col;
#pragma unroll
      for (int n = 0; n < 4; ++n) out[n * 16] = (float)acc[m][n][r] * s * scl[n];
    }
  }
#undef STAGE_A
#undef STAGE_B
#undef LDA_TO
#undef LDB_TO
#undef MFMA16
#undef FENCE
#undef BAR
#undef VM6
#undef SB
}

// ---------------- fallback (only if ws_size too small): tiled fp32 vector GEMM ----------------
__global__ __launch_bounds__(256) void fb_gemm_kernel(const float* __restrict__ X,
                                                      const int* __restrict__ W,
                                                      const float* __restrict__ scale,
                                                      float* __restrict__ Y) {
  __shared__ float xs[16][65];
  __shared__ float ws_[16][65];
  const int bn = blockIdx.x * 64;
  const int bm = blockIdx.y * 64;
  const int tx = threadIdx.x & 15;
  const int ty = threadIdx.x >> 4;
  float acc[4][4] = {};
  for (int k0 = 0; k0 < K_; k0 += 16) {
    for (int i = threadIdx.x; i < 64 * 16; i += 256) {
      int r = i >> 4, c = i & 15;
      xs[c][r] = X[(size_t)(bm + r) * K_ + k0 + c];
    }
    for (int i = threadIdx.x; i < 16 * 64; i += 256) {
      int r = i >> 6, c = i & 63;
      ws_[r][c] = (float)W[(size_t)(k0 + r) * N_ + bn + c];
    }
    __syncthreads();
#pragma unroll
    for (int kk = 0; kk < 16; ++kk) {
      float a[4], b[4];
#pragma unroll
      for (int i = 0; i < 4; ++i) a[i] = xs[kk][ty * 4 + i];
#pragma unroll
      for (int j = 0; j < 4; ++j) b[j] = ws_[kk][tx * 4 + j];
#pragma unroll
      for (int i = 0; i < 4; ++i)
#pragma unroll
        for (int j = 0; j < 4; ++j) acc[i][j] += a[i] * b[j];
    }
    __syncthreads();
  }
#pragma unroll
  for (int i = 0; i < 4; ++i)
#pragma unroll
    for (int j = 0; j < 4; ++j)
      Y[(size_t)(bm + ty * 4 + i) * N_ + bn + tx * 4 + j] = acc[i][j] * scale[bn + tx * 4 + j];
}

extern "C" void kernel_launch(void* const* d_in, const int* in_sizes, int n_in,
                              void* d_out, int out_size, void* d_ws, size_t ws_size,
                              hipStream_t stream) {
  const float* x = (const float*)d_in[0];
  const int* w = (const int*)d_in[1];  // harness materializes int8 weights as int32
  const float* scale = (const float*)d_in[2];
  float* y = (float*)d_out;

  const size_t xq_bytes = (size_t)M_ * K_;
  const size_t sx_off = xq_bytes;
  const size_t wt_off = sx_off + (size_t)M_ * 4;
  const size_t need = wt_off + (size_t)N_ * K_;  // ~161.5 MB

  if (ws_size >= need) {
    signed char* xq = (signed char*)d_ws;
    float* sx = (float*)((char*)d_ws + sx_off);
    signed char* wt = (signed char*)((char*)d_ws + wt_off);
    hipLaunchKernelGGL(quant_x_kernel, dim3(M_), dim3(256), 0, stream, x, xq, sx);
    hipLaunchKernelGGL(transpose_w_kernel, dim3(K_ / 64, N_ / 64), dim3(256), 0, stream, w, wt);
    hipLaunchKernelGGL(gemm_i8_kernel, dim3((M_ / 256) * (N_ / 256)), dim3(512), 0, stream,
                       xq, wt, sx, scale, y);
  } else {
    hipLaunchKernelGGL(fb_gemm_kernel, dim3(N_ / 64, M_ / 64), dim3(256), 0, stream,
                       x, w, scale, y);
  }
}